// Round 17
// baseline (786.414 us; speedup 1.0000x reference)
//
#include <hip/hip_runtime.h>
#include <hip/hip_bf16.h>
#include <math.h>

#define N_NODES 50000
#define N_EDGES 800000
#define N_GRAPHS 512
#define F_IN 16
#define E_DIM 64
#define D 128
#define L_DIM 64
#define NEG_SLOPE 0.01f

#define SCAN_N (N_NODES + 1)                  // 50001
#define NBUCK ((N_NODES + 127) >> 7)          // 391 buckets of 128 nodes

typedef __hip_bfloat16 bf16;
typedef unsigned int uint;
typedef unsigned short ushort;
typedef __attribute__((ext_vector_type(8))) short short8;
typedef __attribute__((ext_vector_type(4))) float float4v;

__device__ __forceinline__ float b2f(bf16 v) { return __bfloat162float(v); }
__device__ __forceinline__ bf16  f2b(float v) { return __float2bfloat16(v); }
__device__ __forceinline__ short f2bs(float f) { bf16 b = __float2bfloat16(f); return *reinterpret_cast<short*>(&b); }
__device__ __forceinline__ float bs2f(short s) { return __uint_as_float(((uint)(ushort)s) << 16); }
__device__ __forceinline__ float leaky(float v) { return v > 0.f ? v : NEG_SLOPE * v; }
__device__ __forceinline__ float sigm(float v) { return 1.f / (1.f + expf(-v)); }

// ---------------------------------------------------------------------------
__global__ __launch_bounds__(256) void k_signal(float* outp, int n)
{
    int i = blockIdx.x * 256 + threadIdx.x;
    if (i < n) outp[i] = 1.0f;
}

// ---------------------------------------------------------------------------
// h0 = leaky(leaky(x@W_emb + b_emb) @ W_first + b_first)  -> bf16
// ---------------------------------------------------------------------------
#define NPE 16
__global__ __launch_bounds__(128) void k_embed(
    const float* __restrict__ x, const float* __restrict__ Wemb, const float* __restrict__ bemb,
    const float* __restrict__ Wfirst, const float* __restrict__ bfirst, bf16* __restrict__ out)
{
    __shared__ float xs[NPE][F_IN];
    __shared__ float ys[NPE][E_DIM];
    int t = threadIdx.x;
    int base = blockIdx.x * NPE;

    for (int i = t; i < NPE * F_IN; i += 128)
        xs[i / F_IN][i % F_IN] = x[(size_t)base * F_IN + i];
    __syncthreads();

    if (t < E_DIM) {
        float acc[NPE];
#pragma unroll
        for (int nn = 0; nn < NPE; nn++) acc[nn] = 0.f;
        for (int k = 0; k < F_IN; k++) {
            float w = Wemb[k * E_DIM + t];
#pragma unroll
            for (int nn = 0; nn < NPE; nn++) acc[nn] += xs[nn][k] * w;
        }
        float bb = bemb[t];
#pragma unroll
        for (int nn = 0; nn < NPE; nn++) ys[nn][t] = leaky(acc[nn] + bb);
    }
    __syncthreads();

    {
        float acc[NPE];
#pragma unroll
        for (int nn = 0; nn < NPE; nn++) acc[nn] = 0.f;
        for (int k = 0; k < E_DIM; k++) {
            float w = Wfirst[k * D + t];
#pragma unroll
            for (int nn = 0; nn < NPE; nn++) acc[nn] += ys[nn][k] * w;
        }
        float bb = bfirst[t];
#pragma unroll
        for (int nn = 0; nn < NPE; nn++)
            out[(size_t)(base + nn) * D + t] = f2b(leaky(acc[nn] + bb));
    }
}

// ---------------------------------------------------------------------------
// Bucketed CSR build (dense writes).  Counts land at bcnt[b+1]; the scan is
// INCLUSIVE so bcnt[b] = sum counts(0..b-1) (R16 bug: exclusive scan double-
// shifted the starts).
// ---------------------------------------------------------------------------
__global__ __launch_bounds__(256) void k_bcount(const int* __restrict__ ei, int* __restrict__ bcnt)
{
    __shared__ int lc[NBUCK];
    for (int i = threadIdx.x; i < NBUCK; i += 256) lc[i] = 0;
    __syncthreads();
    int stride = gridDim.x * 256;
    for (int e = blockIdx.x * 256 + threadIdx.x; e < N_EDGES; e += stride) {
        int d = ei[N_EDGES + e];
        d = d < 0 ? 0 : (d >= N_NODES ? N_NODES - 1 : d);
        atomicAdd(&lc[d >> 7], 1);
    }
    __syncthreads();
    for (int i = threadIdx.x; i < NBUCK; i += 256)
        if (lc[i]) atomicAdd(&bcnt[i + 1], lc[i]);
}

__global__ void k_bscan(int* __restrict__ bcnt)
{
    if (threadIdx.x == 0 && blockIdx.x == 0) {
        int run = 0;
        for (int i = 0; i <= NBUCK; i++) { run += bcnt[i]; bcnt[i] = run; }
    }
}

__global__ __launch_bounds__(256) void k_bfill(
    const int* __restrict__ ei, const int* __restrict__ bstart,
    int* __restrict__ bcur, uint* __restrict__ ebuf)
{
    int e = blockIdx.x * 256 + threadIdx.x;
    if (e < N_EDGES) {
        int s = ei[e];
        int d = ei[N_EDGES + e];
        s = s < 0 ? 0 : (s >= N_NODES ? N_NODES - 1 : s);
        d = d < 0 ? 0 : (d >= N_NODES ? N_NODES - 1 : d);
        int b = d >> 7;
        int slot = bstart[b] + atomicAdd(&bcur[b], 1);
        if (slot >= 0 && slot < N_EDGES)
            ebuf[slot] = ((uint)(d & 127) << 16) | (uint)s;
    }
}

__global__ __launch_bounds__(256) void k_csr(
    const int* __restrict__ bstart, const uint* __restrict__ ebuf,
    int* __restrict__ offs, int* __restrict__ srcs)
{
    __shared__ int cnt[128];
    __shared__ int loffs[129];
    int b = blockIdx.x, t = threadIdx.x;
    int e0 = bstart[b], e1 = bstart[b + 1];
    if (t < 128) cnt[t] = 0;
    __syncthreads();
    for (int j = e0 + t; j < e1; j += 256)
        atomicAdd(&cnt[(ebuf[j] >> 16) & 127], 1);
    __syncthreads();
    if (t == 0) {
        int run = 0;
        for (int i = 0; i < 128; i++) { loffs[i] = run; run += cnt[i]; }
        loffs[128] = run;
    }
    __syncthreads();
    int n0 = b << 7;
    if (t < 128) {
        int n = n0 + t;
        if (n <= N_NODES) offs[n] = e0 + loffs[t];
        cnt[t] = 0;                       // reset for rank pass
    }
    __syncthreads();
    for (int j = e0 + t; j < e1; j += 256) {
        uint pk = ebuf[j];
        int dl = (pk >> 16) & 127;
        int rank = atomicAdd(&cnt[dl], 1);
        int slot = e0 + loffs[dl] + rank;
        if (slot >= 0 && slot < N_EDGES) srcs[slot] = (int)(pk & 0xffffu);
    }
}

// ---------------------------------------------------------------------------
// gstart[g] = lower_bound(batch, g), g in [0, N_GRAPHS] inclusive (513 entries)
// ---------------------------------------------------------------------------
__global__ __launch_bounds__(256) void k_gstart(const int* __restrict__ batch, int* __restrict__ gstart)
{
    int g = blockIdx.x * 256 + threadIdx.x;
    if (g > N_GRAPHS) return;
    int lo = 0, hi = N_NODES;
    while (lo < hi) {
        int mid = (lo + hi) >> 1;
        if (batch[mid] < g) lo = mid + 1; else hi = mid;
    }
    gstart[g] = lo;
}

// ---------------------------------------------------------------------------
// All weight packing (MFMA B-fragment order) in one kernel
// ---------------------------------------------------------------------------
__global__ __launch_bounds__(256) void k_pack_all(
    const float* __restrict__ Wl, const float* __restrict__ Wr,
    const float* __restrict__ gWih, const float* __restrict__ gWhh,
    short* __restrict__ W1p, short* __restrict__ Wihp, short* __restrict__ Whhp)
{
    int tid = blockIdx.x * 256 + threadIdx.x;     // 131072 total
    if (tid < 32768) {
        int j = tid & 7, l = (tid >> 3) & 63, frag = tid >> 9;
        int nb = frag & 7, kb = frag >> 3;
        int k = kb * 32 + ((l >> 4) * 8) + j;
        int n = nb * 16 + (l & 15);
        float v = (k < 128) ? Wl[k * D + n] : Wr[(k - 128) * D + n];
        W1p[tid] = f2bs(v);
    } else {
        int id = tid - 32768;
        const float* W = gWih;
        short* Wp = Wihp;
        if (id >= 49152) { id -= 49152; W = gWhh; Wp = Whhp; }
        int j = id & 7, l = (id >> 3) & 63, frag = id >> 9;
        int nb = frag % 24, kb = frag / 24;
        int k = kb * 32 + ((l >> 4) * 8) + j;
        int n = nb * 16 + (l & 15);
        Wp[id] = f2bs(W[k * 384 + n]);
    }
}

// ---------------------------------------------------------------------------
// High-occupancy neighbor gather: one wave per node, 8x unrolled.
// ---------------------------------------------------------------------------
__global__ __launch_bounds__(256) void k_gather(
    const bf16* __restrict__ hin, bf16* __restrict__ hagg,
    const int* __restrict__ offs, const int* __restrict__ srcs)
{
    int w = threadIdx.x >> 6, l = threadIdx.x & 63;
    int n = blockIdx.x * 4 + w;
    const ushort* hinu = (const ushort*)hin;
    int j0 = offs[n], j1 = offs[n + 1];
    j0 = j0 < 0 ? 0 : (j0 > N_EDGES ? N_EDGES : j0);
    j1 = j1 < j0 ? j0 : (j1 > N_EDGES ? N_EDGES : j1);

    float lo[8], hi8[8];
#pragma unroll
    for (int i = 0; i < 8; i++) { lo[i] = 0.f; hi8[i] = 0.f; }

    int j = j0;
    for (; j + 7 < j1; j += 8) {
        int ss[8];
        uint vv[8];
#pragma unroll
        for (int i = 0; i < 8; i++) {
            int s = srcs[j + i];
            ss[i] = s < 0 ? 0 : (s >= N_NODES ? N_NODES - 1 : s);
        }
#pragma unroll
        for (int i = 0; i < 8; i++)
            vv[i] = *(const uint*)(hinu + (size_t)ss[i] * D + l * 2);
#pragma unroll
        for (int i = 0; i < 8; i++) {
            lo[i] += __uint_as_float(vv[i] << 16);
            hi8[i] += __uint_as_float(vv[i] & 0xffff0000u);
        }
    }
    for (; j < j1; j++) {
        int s = srcs[j];
        s = s < 0 ? 0 : (s >= N_NODES ? N_NODES - 1 : s);
        uint v = *(const uint*)(hinu + (size_t)s * D + l * 2);
        lo[0] += __uint_as_float(v << 16);
        hi8[0] += __uint_as_float(v & 0xffff0000u);
    }
    float a0 = ((lo[0] + lo[1]) + (lo[2] + lo[3])) + ((lo[4] + lo[5]) + (lo[6] + lo[7]));
    float a1 = ((hi8[0] + hi8[1]) + (hi8[2] + hi8[3])) + ((hi8[4] + hi8[5]) + (hi8[6] + hi8[7]));
    uint ap = ((uint)(ushort)f2bs(a1) << 16) | (ushort)f2bs(a0);
    *(uint*)((ushort*)hagg + (size_t)n * D + l * 2) = ap;
}

// ---------------------------------------------------------------------------
// Fused SAGE + GRU via MFMA.  32 rows/block, 2 waves x 1 tile.
// B register double-buffer + Hsh epilogue.
// ---------------------------------------------------------------------------
#define M_STR 136
__global__ __launch_bounds__(128) void k_sage_gru_mfma(
    const bf16* __restrict__ hin, bf16* __restrict__ hagg_out,
    const short* __restrict__ W1p, const short* __restrict__ Wihp, const short* __restrict__ Whhp,
    const float* __restrict__ bl, const float* __restrict__ bih, const float* __restrict__ bhh)
{
    __shared__ short Msh[32 * M_STR];   // 8704 B
    __shared__ short Hsh[32 * M_STR];   // 8704 B
    int t = threadIdx.x;
    int w = t >> 6, l = t & 63;
    int base = blockIdx.x * 32;
    const ushort* hinu = (const ushort*)hin;
    const ushort* haggu = (const ushort*)hagg_out;
    ushort* houtu = (ushort*)hagg_out;

    int r0 = base + w * 16 + (l & 15);
    int rc0 = r0 < N_NODES ? r0 : N_NODES - 1;
    int koff = (l >> 4) * 8;

    short8 afr[8];
#pragma unroll
    for (int k0 = 0; k0 < 4; k0++)
        afr[k0] = *(const short8*)(haggu + (size_t)rc0 * D + k0 * 32 + koff);
#pragma unroll
    for (int k0 = 0; k0 < 4; k0++)
        afr[4 + k0] = *(const short8*)(hinu + (size_t)rc0 * D + k0 * 32 + koff);

    int mrow = w * 16 + (l & 15);
    int crow = w * 16 + (l >> 4) * 4;

    // park h tile in LDS (wave-private rows)
#pragma unroll
    for (int k0 = 0; k0 < 4; k0++)
        *(short8*)&Hsh[mrow * M_STR + k0 * 32 + koff] = afr[4 + k0];

    // ---- GEMM1: m = relu([agg|h] @ W1 + b_l) -> Msh, B double-buffered ----
    short8 bA[8], bB[8];
#pragma unroll
    for (int k0 = 0; k0 < 8; k0++)
        bA[k0] = *(const short8*)&W1p[((k0 * 8 + 0) * 64 + l) * 8];
#pragma unroll
    for (int ct = 0; ct < 8; ct++) {
        const short8* bc = (ct & 1) ? bB : bA;
        short8* bn = (ct & 1) ? bA : bB;
        if (ct < 7) {
#pragma unroll
            for (int k0 = 0; k0 < 8; k0++)
                bn[k0] = *(const short8*)&W1p[((k0 * 8 + ct + 1) * 64 + l) * 8];
        }
        float4v acc = {0.f, 0.f, 0.f, 0.f};
#pragma unroll
        for (int k0 = 0; k0 < 8; k0++)
            acc = __builtin_amdgcn_mfma_f32_16x16x32_bf16(afr[k0], bc[k0], acc, 0, 0, 0);
        float bb = bl[ct * 16 + (l & 15)];
#pragma unroll
        for (int i = 0; i < 4; i++) {
            float v = acc[i] + bb;
            Msh[(crow + i) * M_STR + ct * 16 + (l & 15)] = f2bs(v > 0.f ? v : 0.f);
        }
    }
    __syncthreads();

    short8 amr[4];
#pragma unroll
    for (int k0 = 0; k0 < 4; k0++)
        amr[k0] = *(const short8*)&Msh[mrow * M_STR + k0 * 32 + koff];

    // ---- GEMM2 + GRU epilogue: 24 (ct,p) phases, B double-buffered ----
    short8 iA[4], hA[4], iB[4], hB[4];
#pragma unroll
    for (int k0 = 0; k0 < 4; k0++) {
        iA[k0] = *(const short8*)&Wihp[((k0 * 24 + 0) * 64 + l) * 8];
        hA[k0] = *(const short8*)&Whhp[((k0 * 24 + 0) * 64 + l) * 8];
    }
#pragma unroll
    for (int ct = 0; ct < 8; ct++) {
        int c = ct * 16 + (l & 15);
        float rv[4], zv[4];
#pragma unroll
        for (int p = 0; p < 3; p++) {
            int ph = ct * 3 + p;
            const short8* wi = (ph & 1) ? iB : iA;
            const short8* wh = (ph & 1) ? hB : hA;
            short8* win = (ph & 1) ? iA : iB;
            short8* whn = (ph & 1) ? hA : hB;
            if (ph < 23) {
                int pn = ph + 1;
                int ctn = pn / 3, ppn = pn - ctn * 3;
                int nbn = ppn * 8 + ctn;
#pragma unroll
                for (int k0 = 0; k0 < 4; k0++) {
                    win[k0] = *(const short8*)&Wihp[((k0 * 24 + nbn) * 64 + l) * 8];
                    whn[k0] = *(const short8*)&Whhp[((k0 * 24 + nbn) * 64 + l) * 8];
                }
            }
            float4v ai = {0.f, 0.f, 0.f, 0.f};
            float4v ah = {0.f, 0.f, 0.f, 0.f};
#pragma unroll
            for (int k0 = 0; k0 < 4; k0++) {
                ai = __builtin_amdgcn_mfma_f32_16x16x32_bf16(amr[k0], wi[k0], ai, 0, 0, 0);
                ah = __builtin_amdgcn_mfma_f32_16x16x32_bf16(afr[4 + k0], wh[k0], ah, 0, 0, 0);
            }
            float bis = bih[p * 128 + c];
            float bhs = bhh[p * 128 + c];
            if (p == 0) {
#pragma unroll
                for (int i = 0; i < 4; i++) rv[i] = sigm(ai[i] + bis + ah[i] + bhs);
            } else if (p == 1) {
#pragma unroll
                for (int i = 0; i < 4; i++) zv[i] = sigm(ai[i] + bis + ah[i] + bhs);
            } else {
#pragma unroll
                for (int i = 0; i < 4; i++) {
                    int g0 = base + crow + i;
                    float h0v = bs2f(Hsh[(crow + i) * M_STR + c]);
                    float nv = tanhf(ai[i] + bis + rv[i] * (ah[i] + bhs));
                    if (g0 < N_NODES)
                        houtu[(size_t)g0 * D + c] = (ushort)f2bs((1.f - zv[i]) * nv + zv[i] * h0v);
                }
            }
        }
    }
}

// ---------------------------------------------------------------------------
// Merged Set2Set step: LSTM + pool, 2 graphs per block (weight loads shared).
// ---------------------------------------------------------------------------
#define POOL_CAP 1024
#define LG2 2
__global__ __launch_bounds__(1024) void k_s2s(
    const float* __restrict__ Wih, const float* __restrict__ Whh,
    const float* __restrict__ bih, const float* __restrict__ bhh,
    const bf16* __restrict__ h, const int* __restrict__ gstart,
    float* __restrict__ qstar, float* __restrict__ hh, float* __restrict__ cc, int first)
{
    int g0 = blockIdx.x * LG2;
    int t = threadIdx.x;
    __shared__ float qs[LG2][2 * D];
    __shared__ float hs[LG2][D];
    __shared__ float part[2][LG2][512];
    __shared__ float hnew[LG2][D];
    __shared__ float e_lds[POOL_CAP];
    __shared__ float redM[16], redS[16];
    __shared__ float rpart[8][D];

    for (int i = t; i < LG2 * 2 * D; i += 1024) {
        int g = i / (2 * D), c = i % (2 * D);
        qs[g][c] = first ? 0.f : qstar[(size_t)(g0 + g) * 2 * D + c];
    }
    for (int i = t; i < LG2 * D; i += 1024) {
        int g = i / D, c = i % D;
        hs[g][c] = first ? 0.f : hh[(size_t)(g0 + g) * D + c];
    }
    __syncthreads();

    int c = t & 511, half = t >> 9;
    float a0 = half ? 0.f : (bih[c] + bhh[c]);
    float a1 = a0;
    int qb = half * 128;
#pragma unroll 4
    for (int i = 0; i < 128; i++) {
        int k = qb + i;
        float wv = Wih[(size_t)k * 512 + c];
        a0 += qs[0][k] * wv;
        a1 += qs[1][k] * wv;
    }
    int hb = half * 64;
#pragma unroll 4
    for (int i = 0; i < 64; i++) {
        int k = hb + i;
        float wv = Whh[(size_t)k * 512 + c];
        a0 += hs[0][k] * wv;
        a1 += hs[1][k] * wv;
    }
    part[half][0][c] = a0;
    part[half][1][c] = a1;
    __syncthreads();

    if (t < LG2 * D) {
        int g = t >> 7, tt = t & 127;
        float gi = part[0][g][tt] + part[1][g][tt];
        float gf = part[0][g][D + tt] + part[1][g][D + tt];
        float gg2 = part[0][g][2 * D + tt] + part[1][g][2 * D + tt];
        float go = part[0][g][3 * D + tt] + part[1][g][3 * D + tt];
        float c_old = first ? 0.f : cc[(size_t)(g0 + g) * D + tt];
        float cn = sigm(gf) * c_old + sigm(gi) * tanhf(gg2);
        float hn = sigm(go) * tanhf(cn);
        cc[(size_t)(g0 + g) * D + tt] = cn;
        hh[(size_t)(g0 + g) * D + tt] = hn;
        qstar[(size_t)(g0 + g) * 2 * D + tt] = hn;
        hnew[g][tt] = hn;
    }
    __syncthreads();

    int w = t >> 6, l = t & 63;
    int dim = t & 127, h8 = t >> 7;
    const ushort* hu = (const ushort*)h;

    for (int gg = 0; gg < LG2; gg++) {
        int g = g0 + gg;
        int s0 = gstart[g], s1 = gstart[g + 1];
        s0 = s0 < 0 ? 0 : (s0 > N_NODES ? N_NODES : s0);
        s1 = s1 < s0 ? s0 : (s1 > N_NODES ? N_NODES : s1);
        int cnt = s1 - s0;

        float hq0 = hnew[gg][l];
        float hq1 = hnew[gg][64 + l];
        float m_run = -INFINITY, s_run = 0.f, racc = 0.f;

        for (int c0 = 0; c0 < cnt; c0 += POOL_CAP) {
            int clen = cnt - c0; if (clen > POOL_CAP) clen = POOL_CAP;

            for (int i = w; i < clen; i += 16) {
                int n = s0 + c0 + i;
                float v = bs2f((short)hu[(size_t)n * D + l]) * hq0
                        + bs2f((short)hu[(size_t)n * D + 64 + l]) * hq1;
#pragma unroll
                for (int off = 32; off > 0; off >>= 1) v += __shfl_down(v, off);
                if (l == 0) e_lds[i] = v;
            }
            __syncthreads();

            float m = -INFINITY;
            for (int i = t; i < clen; i += 1024) m = fmaxf(m, e_lds[i]);
#pragma unroll
            for (int off = 32; off > 0; off >>= 1) m = fmaxf(m, __shfl_down(m, off));
            if (l == 0) redM[w] = m;
            __syncthreads();
            m = -INFINITY;
#pragma unroll
            for (int i = 0; i < 16; i++) m = fmaxf(m, redM[i]);
            float m_new = fmaxf(m_run, m);
            float scale = (m_run == -INFINITY) ? 0.f : expf(m_run - m_new);
            s_run *= scale;
            racc *= scale;
            __syncthreads();

            float s = 0.f;
            for (int i = t; i < clen; i += 1024) {
                float wv = expf(e_lds[i] - m_new);
                e_lds[i] = wv;
                s += wv;
            }
#pragma unroll
            for (int off = 32; off > 0; off >>= 1) s += __shfl_down(s, off);
            if (l == 0) redS[w] = s;
            __syncthreads();
#pragma unroll
            for (int i = 0; i < 16; i++) s_run += redS[i];

            for (int i = h8; i < clen; i += 8)
                racc += e_lds[i] * bs2f((short)hu[(size_t)(s0 + c0 + i) * D + dim]);
            m_run = m_new;
            __syncthreads();
        }

        rpart[h8][dim] = racc;
        __syncthreads();
        if (t < D) {
            float inv = 1.f / (s_run + 1e-16f);
            float r = 0.f;
#pragma unroll
            for (int i = 0; i < 8; i++) r += rpart[i][t];
            qstar[(size_t)g * 2 * D + D + t] = r * inv;
        }
        __syncthreads();
    }
}

// ---------------------------------------------------------------------------
// Head: y = leaky(q_star@W_lin + b_lin) @ W_fin + b_fin   -> fp32 out
// ---------------------------------------------------------------------------
__global__ __launch_bounds__(128) void k_final(
    const float* __restrict__ qstar, const float* __restrict__ Wlin, const float* __restrict__ blin,
    const float* __restrict__ Wfin, const float* __restrict__ bfin, float* __restrict__ outp)
{
    int g = blockIdx.x, t = threadIdx.x;
    __shared__ float qs[2 * D], ts[D];
    qs[t] = qstar[(size_t)g * 2 * D + t];
    qs[D + t] = qstar[(size_t)g * 2 * D + D + t];
    __syncthreads();

    float acc = blin[t];
    for (int k = 0; k < 2 * D; k++) acc += qs[k] * Wlin[(size_t)k * D + t];
    ts[t] = leaky(acc);
    __syncthreads();

    if (t < L_DIM) {
        float a2 = bfin[t];
        for (int k = 0; k < D; k++) a2 += ts[k] * Wfin[(size_t)k * L_DIM + t];
        outp[(size_t)g * L_DIM + t] = a2;
    }
}

// ---------------------------------------------------------------------------
extern "C" void kernel_launch(void* const* d_in, const int* in_sizes, int n_in,
                              void* d_out, int out_size, void* d_ws, size_t ws_size,
                              hipStream_t stream)
{
    const float* x      = (const float*)d_in[0];
    const int*   ei     = (const int*)d_in[1];
    const int*   batch  = (const int*)d_in[3];
    const float* Wemb   = (const float*)d_in[4];
    const float* bemb   = (const float*)d_in[5];
    const float* Wfirst = (const float*)d_in[6];
    const float* bfirst = (const float*)d_in[7];
    const float* Wl     = (const float*)d_in[8];
    const float* bl     = (const float*)d_in[9];
    const float* Wr     = (const float*)d_in[10];
    const float* gWih   = (const float*)d_in[11];
    const float* gWhh   = (const float*)d_in[12];
    const float* gbih   = (const float*)d_in[13];
    const float* gbhh   = (const float*)d_in[14];
    const float* lWih   = (const float*)d_in[15];
    const float* lWhh   = (const float*)d_in[16];
    const float* lbih   = (const float*)d_in[17];
    const float* lbhh   = (const float*)d_in[18];
    const float* Wlin   = (const float*)d_in[19];
    const float* blin   = (const float*)d_in[20];
    const float* Wfin   = (const float*)d_in[21];
    const float* bfin   = (const float*)d_in[22];
    float* outp = (float*)d_out;

    // ---- workspace carve (256B-aligned slabs), ~33 MB ----
    size_t o = 0;
    char* base = (char*)d_ws;
    auto carve = [&](size_t bytes) { void* p = base + o; o += (bytes + 255) & ~(size_t)255; return p; };
    bf16*  h0     = (bf16*)carve((size_t)N_NODES * D * sizeof(bf16));
    bf16*  h1     = (bf16*)carve((size_t)N_NODES * D * sizeof(bf16));
    int*   offs   = (int*)carve((size_t)SCAN_N * sizeof(int));
    int*   srcs   = (int*)carve((size_t)N_EDGES * sizeof(int));
    int*   bcnt   = (int*)carve((size_t)(NBUCK + 1) * sizeof(int));
    int*   bcur   = (int*)carve((size_t)NBUCK * sizeof(int));
    uint*  ebuf   = (uint*)carve((size_t)N_EDGES * sizeof(uint));
    float* hh     = (float*)carve((size_t)N_GRAPHS * D * sizeof(float));
    float* cc     = (float*)carve((size_t)N_GRAPHS * D * sizeof(float));
    float* qstar  = (float*)carve((size_t)N_GRAPHS * 2 * D * sizeof(float));
    int*   gstart = (int*)carve((size_t)(N_GRAPHS + 1) * sizeof(int));
    short* W1p    = (short*)carve((size_t)256 * 128 * sizeof(short));
    short* Wihp   = (short*)carve((size_t)128 * 384 * sizeof(short));
    short* Whhp   = (short*)carve((size_t)128 * 384 * sizeof(short));
    size_t need = o;

    if (ws_size < need) {
        k_signal<<<(out_size + 255) / 256, 256, 0, stream>>>(outp, out_size);
        return;
    }

    // node MLP -> h0
    k_embed<<<N_NODES / NPE, 128, 0, stream>>>(x, Wemb, bemb, Wfirst, bfirst, h0);

    // all weight packing
    k_pack_all<<<(32768 + 98304) / 256, 256, 0, stream>>>(Wl, Wr, gWih, gWhh, W1p, Wihp, Whhp);

    // bucketed CSR build (dense writes)
    hipMemsetAsync(bcnt, 0, (size_t)((char*)ebuf - (char*)bcnt), stream);
    k_bcount<<<128, 256, 0, stream>>>(ei, bcnt);
    k_bscan<<<1, 64, 0, stream>>>(bcnt);
    k_bfill<<<(N_EDGES + 255) / 256, 256, 0, stream>>>(ei, bcnt, bcur, ebuf);
    k_csr<<<NBUCK, 256, 0, stream>>>(bcnt, ebuf, offs, srcs);

    // graph segment starts
    k_gstart<<<(N_GRAPHS + 1 + 255) / 256, 256, 0, stream>>>(batch, gstart);

    // 3 message-passing steps
    bf16* hc = h0; bf16* hn = h1;
    for (int s = 0; s < 3; s++) {
        k_gather<<<N_NODES / 4, 256, 0, stream>>>(hc, hn, offs, srcs);
        k_sage_gru_mfma<<<(N_NODES + 31) / 32, 128, 0, stream>>>(
            hc, hn, W1p, Wihp, Whhp, bl, gbih, gbhh);
        bf16* tmp = hc; hc = hn; hn = tmp;
    }

    // Set2Set: merged LSTM+pool, 2 graphs/block
    for (int s = 0; s < 3; s++) {
        k_s2s<<<N_GRAPHS / LG2, 1024, 0, stream>>>(lWih, lWhh, lbih, lbhh,
                                                   hc, gstart, qstar, hh, cc, s == 0);
    }

    k_final<<<N_GRAPHS, 128, 0, stream>>>(qstar, Wlin, blin, Wfin, bfin, outp);
}

// Round 18
// 512.136 us; speedup vs baseline: 1.5356x; 1.5356x over previous
//
#include <hip/hip_runtime.h>
#include <hip/hip_bf16.h>
#include <math.h>

#define N_NODES 50000
#define N_EDGES 800000
#define N_GRAPHS 512
#define F_IN 16
#define E_DIM 64
#define D 128
#define L_DIM 64
#define NEG_SLOPE 0.01f

#define SCAN_N (N_NODES + 1)                  // 50001
#define NBUCK ((N_NODES + 127) >> 7)          // 391 buckets of 128 nodes
#define EPT 4
#define BFT 1024
#define EPB (BFT * EPT)                       // 4096 edges per block

typedef __hip_bfloat16 bf16;
typedef unsigned int uint;
typedef unsigned short ushort;
typedef __attribute__((ext_vector_type(8))) short short8;
typedef __attribute__((ext_vector_type(4))) float float4v;

__device__ __forceinline__ float b2f(bf16 v) { return __bfloat162float(v); }
__device__ __forceinline__ bf16  f2b(float v) { return __float2bfloat16(v); }
__device__ __forceinline__ short f2bs(float f) { bf16 b = __float2bfloat16(f); return *reinterpret_cast<short*>(&b); }
__device__ __forceinline__ float bs2f(short s) { return __uint_as_float(((uint)(ushort)s) << 16); }
__device__ __forceinline__ float leaky(float v) { return v > 0.f ? v : NEG_SLOPE * v; }
__device__ __forceinline__ float sigm(float v) { return 1.f / (1.f + expf(-v)); }

// ---------------------------------------------------------------------------
__global__ __launch_bounds__(256) void k_signal(float* outp, int n)
{
    int i = blockIdx.x * 256 + threadIdx.x;
    if (i < n) outp[i] = 1.0f;
}

// ---------------------------------------------------------------------------
// h0 = leaky(leaky(x@W_emb + b_emb) @ W_first + b_first)  -> bf16
// ---------------------------------------------------------------------------
#define NPE 16
__global__ __launch_bounds__(128) void k_embed(
    const float* __restrict__ x, const float* __restrict__ Wemb, const float* __restrict__ bemb,
    const float* __restrict__ Wfirst, const float* __restrict__ bfirst, bf16* __restrict__ out)
{
    __shared__ float xs[NPE][F_IN];
    __shared__ float ys[NPE][E_DIM];
    int t = threadIdx.x;
    int base = blockIdx.x * NPE;

    for (int i = t; i < NPE * F_IN; i += 128)
        xs[i / F_IN][i % F_IN] = x[(size_t)base * F_IN + i];
    __syncthreads();

    if (t < E_DIM) {
        float acc[NPE];
#pragma unroll
        for (int nn = 0; nn < NPE; nn++) acc[nn] = 0.f;
        for (int k = 0; k < F_IN; k++) {
            float w = Wemb[k * E_DIM + t];
#pragma unroll
            for (int nn = 0; nn < NPE; nn++) acc[nn] += xs[nn][k] * w;
        }
        float bb = bemb[t];
#pragma unroll
        for (int nn = 0; nn < NPE; nn++) ys[nn][t] = leaky(acc[nn] + bb);
    }
    __syncthreads();

    {
        float acc[NPE];
#pragma unroll
        for (int nn = 0; nn < NPE; nn++) acc[nn] = 0.f;
        for (int k = 0; k < E_DIM; k++) {
            float w = Wfirst[k * D + t];
#pragma unroll
            for (int nn = 0; nn < NPE; nn++) acc[nn] += ys[nn][k] * w;
        }
        float bb = bfirst[t];
#pragma unroll
        for (int nn = 0; nn < NPE; nn++)
            out[(size_t)(base + nn) * D + t] = f2b(leaky(acc[nn] + bb));
    }
}

// ---------------------------------------------------------------------------
// Bucketed CSR build.  bcnt counts land at [b+1]; INCLUSIVE scan -> starts.
// k_bfill2: LDS-aggregated placement — one global atomic per (block,bucket)
// (76K total vs 800K in R17's contention wall), contiguous per-group writes.
// ---------------------------------------------------------------------------
__global__ __launch_bounds__(256) void k_bcount(const int* __restrict__ ei, int* __restrict__ bcnt)
{
    __shared__ int lc[NBUCK];
    for (int i = threadIdx.x; i < NBUCK; i += 256) lc[i] = 0;
    __syncthreads();
    int stride = gridDim.x * 256;
    for (int e = blockIdx.x * 256 + threadIdx.x; e < N_EDGES; e += stride) {
        int d = ei[N_EDGES + e];
        d = d < 0 ? 0 : (d >= N_NODES ? N_NODES - 1 : d);
        atomicAdd(&lc[d >> 7], 1);
    }
    __syncthreads();
    for (int i = threadIdx.x; i < NBUCK; i += 256)
        if (lc[i]) atomicAdd(&bcnt[i + 1], lc[i]);
}

__global__ void k_bscan(int* __restrict__ bcnt)
{
    if (threadIdx.x == 0 && blockIdx.x == 0) {
        int run = 0;
        for (int i = 0; i <= NBUCK; i++) { run += bcnt[i]; bcnt[i] = run; }
    }
}

__global__ __launch_bounds__(BFT) void k_bfill2(
    const int* __restrict__ ei, const int* __restrict__ bstart,
    int* __restrict__ bcur, uint* __restrict__ ebuf)
{
    __shared__ int lcnt[NBUCK];
    __shared__ int lbase[NBUCK];
    int t = threadIdx.x;
    int e0 = blockIdx.x * EPB;

    for (int i = t; i < NBUCK; i += BFT) lcnt[i] = 0;
    __syncthreads();

    uint pk[EPT];
    int bb[EPT];
#pragma unroll
    for (int q = 0; q < EPT; q++) {
        int e = e0 + q * BFT + t;          // coalesced reads
        bb[q] = -1;
        if (e < N_EDGES) {
            int s = ei[e];
            int d = ei[N_EDGES + e];
            s = s < 0 ? 0 : (s >= N_NODES ? N_NODES - 1 : s);
            d = d < 0 ? 0 : (d >= N_NODES ? N_NODES - 1 : d);
            bb[q] = d >> 7;
            pk[q] = ((uint)(d & 127) << 16) | (uint)s;
            atomicAdd(&lcnt[bb[q]], 1);    // LDS atomic (fast)
        }
    }
    __syncthreads();

    // reserve one contiguous global range per non-empty bucket
    for (int i = t; i < NBUCK; i += BFT) {
        int cv = lcnt[i];
        lbase[i] = cv > 0 ? atomicAdd(&bcur[i], cv) : 0;
    }
    __syncthreads();
    for (int i = t; i < NBUCK; i += BFT) lcnt[i] = 0;   // reuse as cursor
    __syncthreads();

#pragma unroll
    for (int q = 0; q < EPT; q++) {
        if (bb[q] >= 0) {
            int pos = lbase[bb[q]] + atomicAdd(&lcnt[bb[q]], 1);
            int slot = bstart[bb[q]] + pos;
            if (slot >= 0 && slot < N_EDGES) ebuf[slot] = pk[q];
        }
    }
}

__global__ __launch_bounds__(256) void k_csr(
    const int* __restrict__ bstart, const uint* __restrict__ ebuf,
    int* __restrict__ offs, int* __restrict__ srcs)
{
    __shared__ int cnt[128];
    __shared__ int loffs[129];
    int b = blockIdx.x, t = threadIdx.x;
    int e0 = bstart[b], e1 = bstart[b + 1];
    if (t < 128) cnt[t] = 0;
    __syncthreads();
    for (int j = e0 + t; j < e1; j += 256)
        atomicAdd(&cnt[(ebuf[j] >> 16) & 127], 1);
    __syncthreads();
    if (t == 0) {
        int run = 0;
        for (int i = 0; i < 128; i++) { loffs[i] = run; run += cnt[i]; }
        loffs[128] = run;
    }
    __syncthreads();
    int n0 = b << 7;
    if (t < 128) {
        int n = n0 + t;
        if (n <= N_NODES) offs[n] = e0 + loffs[t];
        cnt[t] = 0;                       // reset for rank pass
    }
    __syncthreads();
    for (int j = e0 + t; j < e1; j += 256) {
        uint pk = ebuf[j];
        int dl = (pk >> 16) & 127;
        int rank = atomicAdd(&cnt[dl], 1);
        int slot = e0 + loffs[dl] + rank;
        if (slot >= 0 && slot < N_EDGES) srcs[slot] = (int)(pk & 0xffffu);
    }
}

// ---------------------------------------------------------------------------
// gstart[g] = lower_bound(batch, g), g in [0, N_GRAPHS] inclusive (513 entries)
// ---------------------------------------------------------------------------
__global__ __launch_bounds__(256) void k_gstart(const int* __restrict__ batch, int* __restrict__ gstart)
{
    int g = blockIdx.x * 256 + threadIdx.x;
    if (g > N_GRAPHS) return;
    int lo = 0, hi = N_NODES;
    while (lo < hi) {
        int mid = (lo + hi) >> 1;
        if (batch[mid] < g) lo = mid + 1; else hi = mid;
    }
    gstart[g] = lo;
}

// ---------------------------------------------------------------------------
// All weight packing (MFMA B-fragment order) in one kernel
// ---------------------------------------------------------------------------
__global__ __launch_bounds__(256) void k_pack_all(
    const float* __restrict__ Wl, const float* __restrict__ Wr,
    const float* __restrict__ gWih, const float* __restrict__ gWhh,
    short* __restrict__ W1p, short* __restrict__ Wihp, short* __restrict__ Whhp)
{
    int tid = blockIdx.x * 256 + threadIdx.x;     // 131072 total
    if (tid < 32768) {
        int j = tid & 7, l = (tid >> 3) & 63, frag = tid >> 9;
        int nb = frag & 7, kb = frag >> 3;
        int k = kb * 32 + ((l >> 4) * 8) + j;
        int n = nb * 16 + (l & 15);
        float v = (k < 128) ? Wl[k * D + n] : Wr[(k - 128) * D + n];
        W1p[tid] = f2bs(v);
    } else {
        int id = tid - 32768;
        const float* W = gWih;
        short* Wp = Wihp;
        if (id >= 49152) { id -= 49152; W = gWhh; Wp = Whhp; }
        int j = id & 7, l = (id >> 3) & 63, frag = id >> 9;
        int nb = frag % 24, kb = frag / 24;
        int k = kb * 32 + ((l >> 4) * 8) + j;
        int n = nb * 16 + (l & 15);
        Wp[id] = f2bs(W[k * 384 + n]);
    }
}

// ---------------------------------------------------------------------------
// High-occupancy neighbor gather: one wave per node, 8x unrolled.
// ---------------------------------------------------------------------------
__global__ __launch_bounds__(256) void k_gather(
    const bf16* __restrict__ hin, bf16* __restrict__ hagg,
    const int* __restrict__ offs, const int* __restrict__ srcs)
{
    int w = threadIdx.x >> 6, l = threadIdx.x & 63;
    int n = blockIdx.x * 4 + w;
    const ushort* hinu = (const ushort*)hin;
    int j0 = offs[n], j1 = offs[n + 1];
    j0 = j0 < 0 ? 0 : (j0 > N_EDGES ? N_EDGES : j0);
    j1 = j1 < j0 ? j0 : (j1 > N_EDGES ? N_EDGES : j1);

    float lo[8], hi8[8];
#pragma unroll
    for (int i = 0; i < 8; i++) { lo[i] = 0.f; hi8[i] = 0.f; }

    int j = j0;
    for (; j + 7 < j1; j += 8) {
        int ss[8];
        uint vv[8];
#pragma unroll
        for (int i = 0; i < 8; i++) {
            int s = srcs[j + i];
            ss[i] = s < 0 ? 0 : (s >= N_NODES ? N_NODES - 1 : s);
        }
#pragma unroll
        for (int i = 0; i < 8; i++)
            vv[i] = *(const uint*)(hinu + (size_t)ss[i] * D + l * 2);
#pragma unroll
        for (int i = 0; i < 8; i++) {
            lo[i] += __uint_as_float(vv[i] << 16);
            hi8[i] += __uint_as_float(vv[i] & 0xffff0000u);
        }
    }
    for (; j < j1; j++) {
        int s = srcs[j];
        s = s < 0 ? 0 : (s >= N_NODES ? N_NODES - 1 : s);
        uint v = *(const uint*)(hinu + (size_t)s * D + l * 2);
        lo[0] += __uint_as_float(v << 16);
        hi8[0] += __uint_as_float(v & 0xffff0000u);
    }
    float a0 = ((lo[0] + lo[1]) + (lo[2] + lo[3])) + ((lo[4] + lo[5]) + (lo[6] + lo[7]));
    float a1 = ((hi8[0] + hi8[1]) + (hi8[2] + hi8[3])) + ((hi8[4] + hi8[5]) + (hi8[6] + hi8[7]));
    uint ap = ((uint)(ushort)f2bs(a1) << 16) | (ushort)f2bs(a0);
    *(uint*)((ushort*)hagg + (size_t)n * D + l * 2) = ap;
}

// ---------------------------------------------------------------------------
// Fused SAGE + GRU via MFMA.  32 rows/block, 2 waves x 1 tile.
// B register double-buffer + Hsh epilogue.
// ---------------------------------------------------------------------------
#define M_STR 136
__global__ __launch_bounds__(128) void k_sage_gru_mfma(
    const bf16* __restrict__ hin, bf16* __restrict__ hagg_out,
    const short* __restrict__ W1p, const short* __restrict__ Wihp, const short* __restrict__ Whhp,
    const float* __restrict__ bl, const float* __restrict__ bih, const float* __restrict__ bhh)
{
    __shared__ short Msh[32 * M_STR];   // 8704 B
    __shared__ short Hsh[32 * M_STR];   // 8704 B
    int t = threadIdx.x;
    int w = t >> 6, l = t & 63;
    int base = blockIdx.x * 32;
    const ushort* hinu = (const ushort*)hin;
    const ushort* haggu = (const ushort*)hagg_out;
    ushort* houtu = (ushort*)hagg_out;

    int r0 = base + w * 16 + (l & 15);
    int rc0 = r0 < N_NODES ? r0 : N_NODES - 1;
    int koff = (l >> 4) * 8;

    short8 afr[8];
#pragma unroll
    for (int k0 = 0; k0 < 4; k0++)
        afr[k0] = *(const short8*)(haggu + (size_t)rc0 * D + k0 * 32 + koff);
#pragma unroll
    for (int k0 = 0; k0 < 4; k0++)
        afr[4 + k0] = *(const short8*)(hinu + (size_t)rc0 * D + k0 * 32 + koff);

    int mrow = w * 16 + (l & 15);
    int crow = w * 16 + (l >> 4) * 4;

    // park h tile in LDS (wave-private rows)
#pragma unroll
    for (int k0 = 0; k0 < 4; k0++)
        *(short8*)&Hsh[mrow * M_STR + k0 * 32 + koff] = afr[4 + k0];

    // ---- GEMM1: m = relu([agg|h] @ W1 + b_l) -> Msh, B double-buffered ----
    short8 bA[8], bB[8];
#pragma unroll
    for (int k0 = 0; k0 < 8; k0++)
        bA[k0] = *(const short8*)&W1p[((k0 * 8 + 0) * 64 + l) * 8];
#pragma unroll
    for (int ct = 0; ct < 8; ct++) {
        const short8* bc = (ct & 1) ? bB : bA;
        short8* bn = (ct & 1) ? bA : bB;
        if (ct < 7) {
#pragma unroll
            for (int k0 = 0; k0 < 8; k0++)
                bn[k0] = *(const short8*)&W1p[((k0 * 8 + ct + 1) * 64 + l) * 8];
        }
        float4v acc = {0.f, 0.f, 0.f, 0.f};
#pragma unroll
        for (int k0 = 0; k0 < 8; k0++)
            acc = __builtin_amdgcn_mfma_f32_16x16x32_bf16(afr[k0], bc[k0], acc, 0, 0, 0);
        float bb = bl[ct * 16 + (l & 15)];
#pragma unroll
        for (int i = 0; i < 4; i++) {
            float v = acc[i] + bb;
            Msh[(crow + i) * M_STR + ct * 16 + (l & 15)] = f2bs(v > 0.f ? v : 0.f);
        }
    }
    __syncthreads();

    short8 amr[4];
#pragma unroll
    for (int k0 = 0; k0 < 4; k0++)
        amr[k0] = *(const short8*)&Msh[mrow * M_STR + k0 * 32 + koff];

    // ---- GEMM2 + GRU epilogue: 24 (ct,p) phases, B double-buffered ----
    short8 iA[4], hA[4], iB[4], hB[4];
#pragma unroll
    for (int k0 = 0; k0 < 4; k0++) {
        iA[k0] = *(const short8*)&Wihp[((k0 * 24 + 0) * 64 + l) * 8];
        hA[k0] = *(const short8*)&Whhp[((k0 * 24 + 0) * 64 + l) * 8];
    }
#pragma unroll
    for (int ct = 0; ct < 8; ct++) {
        int c = ct * 16 + (l & 15);
        float rv[4], zv[4];
#pragma unroll
        for (int p = 0; p < 3; p++) {
            int ph = ct * 3 + p;
            const short8* wi = (ph & 1) ? iB : iA;
            const short8* wh = (ph & 1) ? hB : hA;
            short8* win = (ph & 1) ? iA : iB;
            short8* whn = (ph & 1) ? hA : hB;
            if (ph < 23) {
                int pn = ph + 1;
                int ctn = pn / 3, ppn = pn - ctn * 3;
                int nbn = ppn * 8 + ctn;
#pragma unroll
                for (int k0 = 0; k0 < 4; k0++) {
                    win[k0] = *(const short8*)&Wihp[((k0 * 24 + nbn) * 64 + l) * 8];
                    whn[k0] = *(const short8*)&Whhp[((k0 * 24 + nbn) * 64 + l) * 8];
                }
            }
            float4v ai = {0.f, 0.f, 0.f, 0.f};
            float4v ah = {0.f, 0.f, 0.f, 0.f};
#pragma unroll
            for (int k0 = 0; k0 < 4; k0++) {
                ai = __builtin_amdgcn_mfma_f32_16x16x32_bf16(amr[k0], wi[k0], ai, 0, 0, 0);
                ah = __builtin_amdgcn_mfma_f32_16x16x32_bf16(afr[4 + k0], wh[k0], ah, 0, 0, 0);
            }
            float bis = bih[p * 128 + c];
            float bhs = bhh[p * 128 + c];
            if (p == 0) {
#pragma unroll
                for (int i = 0; i < 4; i++) rv[i] = sigm(ai[i] + bis + ah[i] + bhs);
            } else if (p == 1) {
#pragma unroll
                for (int i = 0; i < 4; i++) zv[i] = sigm(ai[i] + bis + ah[i] + bhs);
            } else {
#pragma unroll
                for (int i = 0; i < 4; i++) {
                    int g0 = base + crow + i;
                    float h0v = bs2f(Hsh[(crow + i) * M_STR + c]);
                    float nv = tanhf(ai[i] + bis + rv[i] * (ah[i] + bhs));
                    if (g0 < N_NODES)
                        houtu[(size_t)g0 * D + c] = (ushort)f2bs((1.f - zv[i]) * nv + zv[i] * h0v);
                }
            }
        }
    }
}

// ---------------------------------------------------------------------------
// Merged Set2Set step: LSTM + pool, 2 graphs per block (weight loads shared).
// ---------------------------------------------------------------------------
#define POOL_CAP 1024
#define LG2 2
__global__ __launch_bounds__(1024) void k_s2s(
    const float* __restrict__ Wih, const float* __restrict__ Whh,
    const float* __restrict__ bih, const float* __restrict__ bhh,
    const bf16* __restrict__ h, const int* __restrict__ gstart,
    float* __restrict__ qstar, float* __restrict__ hh, float* __restrict__ cc, int first)
{
    int g0 = blockIdx.x * LG2;
    int t = threadIdx.x;
    __shared__ float qs[LG2][2 * D];
    __shared__ float hs[LG2][D];
    __shared__ float part[2][LG2][512];
    __shared__ float hnew[LG2][D];
    __shared__ float e_lds[POOL_CAP];
    __shared__ float redM[16], redS[16];
    __shared__ float rpart[8][D];

    for (int i = t; i < LG2 * 2 * D; i += 1024) {
        int g = i / (2 * D), c = i % (2 * D);
        qs[g][c] = first ? 0.f : qstar[(size_t)(g0 + g) * 2 * D + c];
    }
    for (int i = t; i < LG2 * D; i += 1024) {
        int g = i / D, c = i % D;
        hs[g][c] = first ? 0.f : hh[(size_t)(g0 + g) * D + c];
    }
    __syncthreads();

    int c = t & 511, half = t >> 9;
    float a0 = half ? 0.f : (bih[c] + bhh[c]);
    float a1 = a0;
    int qb = half * 128;
#pragma unroll 4
    for (int i = 0; i < 128; i++) {
        int k = qb + i;
        float wv = Wih[(size_t)k * 512 + c];
        a0 += qs[0][k] * wv;
        a1 += qs[1][k] * wv;
    }
    int hb = half * 64;
#pragma unroll 4
    for (int i = 0; i < 64; i++) {
        int k = hb + i;
        float wv = Whh[(size_t)k * 512 + c];
        a0 += hs[0][k] * wv;
        a1 += hs[1][k] * wv;
    }
    part[half][0][c] = a0;
    part[half][1][c] = a1;
    __syncthreads();

    if (t < LG2 * D) {
        int g = t >> 7, tt = t & 127;
        float gi = part[0][g][tt] + part[1][g][tt];
        float gf = part[0][g][D + tt] + part[1][g][D + tt];
        float gg2 = part[0][g][2 * D + tt] + part[1][g][2 * D + tt];
        float go = part[0][g][3 * D + tt] + part[1][g][3 * D + tt];
        float c_old = first ? 0.f : cc[(size_t)(g0 + g) * D + tt];
        float cn = sigm(gf) * c_old + sigm(gi) * tanhf(gg2);
        float hn = sigm(go) * tanhf(cn);
        cc[(size_t)(g0 + g) * D + tt] = cn;
        hh[(size_t)(g0 + g) * D + tt] = hn;
        qstar[(size_t)(g0 + g) * 2 * D + tt] = hn;
        hnew[g][tt] = hn;
    }
    __syncthreads();

    int w = t >> 6, l = t & 63;
    int dim = t & 127, h8 = t >> 7;
    const ushort* hu = (const ushort*)h;

    for (int gg = 0; gg < LG2; gg++) {
        int g = g0 + gg;
        int s0 = gstart[g], s1 = gstart[g + 1];
        s0 = s0 < 0 ? 0 : (s0 > N_NODES ? N_NODES : s0);
        s1 = s1 < s0 ? s0 : (s1 > N_NODES ? N_NODES : s1);
        int cnt = s1 - s0;

        float hq0 = hnew[gg][l];
        float hq1 = hnew[gg][64 + l];
        float m_run = -INFINITY, s_run = 0.f, racc = 0.f;

        for (int c0 = 0; c0 < cnt; c0 += POOL_CAP) {
            int clen = cnt - c0; if (clen > POOL_CAP) clen = POOL_CAP;

            for (int i = w; i < clen; i += 16) {
                int n = s0 + c0 + i;
                float v = bs2f((short)hu[(size_t)n * D + l]) * hq0
                        + bs2f((short)hu[(size_t)n * D + 64 + l]) * hq1;
#pragma unroll
                for (int off = 32; off > 0; off >>= 1) v += __shfl_down(v, off);
                if (l == 0) e_lds[i] = v;
            }
            __syncthreads();

            float m = -INFINITY;
            for (int i = t; i < clen; i += 1024) m = fmaxf(m, e_lds[i]);
#pragma unroll
            for (int off = 32; off > 0; off >>= 1) m = fmaxf(m, __shfl_down(m, off));
            if (l == 0) redM[w] = m;
            __syncthreads();
            m = -INFINITY;
#pragma unroll
            for (int i = 0; i < 16; i++) m = fmaxf(m, redM[i]);
            float m_new = fmaxf(m_run, m);
            float scale = (m_run == -INFINITY) ? 0.f : expf(m_run - m_new);
            s_run *= scale;
            racc *= scale;
            __syncthreads();

            float s = 0.f;
            for (int i = t; i < clen; i += 1024) {
                float wv = expf(e_lds[i] - m_new);
                e_lds[i] = wv;
                s += wv;
            }
#pragma unroll
            for (int off = 32; off > 0; off >>= 1) s += __shfl_down(s, off);
            if (l == 0) redS[w] = s;
            __syncthreads();
#pragma unroll
            for (int i = 0; i < 16; i++) s_run += redS[i];

            for (int i = h8; i < clen; i += 8)
                racc += e_lds[i] * bs2f((short)hu[(size_t)(s0 + c0 + i) * D + dim]);
            m_run = m_new;
            __syncthreads();
        }

        rpart[h8][dim] = racc;
        __syncthreads();
        if (t < D) {
            float inv = 1.f / (s_run + 1e-16f);
            float r = 0.f;
#pragma unroll
            for (int i = 0; i < 8; i++) r += rpart[i][t];
            qstar[(size_t)g * 2 * D + D + t] = r * inv;
        }
        __syncthreads();
    }
}

// ---------------------------------------------------------------------------
// Head: y = leaky(q_star@W_lin + b_lin) @ W_fin + b_fin   -> fp32 out
// ---------------------------------------------------------------------------
__global__ __launch_bounds__(128) void k_final(
    const float* __restrict__ qstar, const float* __restrict__ Wlin, const float* __restrict__ blin,
    const float* __restrict__ Wfin, const float* __restrict__ bfin, float* __restrict__ outp)
{
    int g = blockIdx.x, t = threadIdx.x;
    __shared__ float qs[2 * D], ts[D];
    qs[t] = qstar[(size_t)g * 2 * D + t];
    qs[D + t] = qstar[(size_t)g * 2 * D + D + t];
    __syncthreads();

    float acc = blin[t];
    for (int k = 0; k < 2 * D; k++) acc += qs[k] * Wlin[(size_t)k * D + t];
    ts[t] = leaky(acc);
    __syncthreads();

    if (t < L_DIM) {
        float a2 = bfin[t];
        for (int k = 0; k < D; k++) a2 += ts[k] * Wfin[(size_t)k * L_DIM + t];
        outp[(size_t)g * L_DIM + t] = a2;
    }
}

// ---------------------------------------------------------------------------
extern "C" void kernel_launch(void* const* d_in, const int* in_sizes, int n_in,
                              void* d_out, int out_size, void* d_ws, size_t ws_size,
                              hipStream_t stream)
{
    const float* x      = (const float*)d_in[0];
    const int*   ei     = (const int*)d_in[1];
    const int*   batch  = (const int*)d_in[3];
    const float* Wemb   = (const float*)d_in[4];
    const float* bemb   = (const float*)d_in[5];
    const float* Wfirst = (const float*)d_in[6];
    const float* bfirst = (const float*)d_in[7];
    const float* Wl     = (const float*)d_in[8];
    const float* bl     = (const float*)d_in[9];
    const float* Wr     = (const float*)d_in[10];
    const float* gWih   = (const float*)d_in[11];
    const float* gWhh   = (const float*)d_in[12];
    const float* gbih   = (const float*)d_in[13];
    const float* gbhh   = (const float*)d_in[14];
    const float* lWih   = (const float*)d_in[15];
    const float* lWhh   = (const float*)d_in[16];
    const float* lbih   = (const float*)d_in[17];
    const float* lbhh   = (const float*)d_in[18];
    const float* Wlin   = (const float*)d_in[19];
    const float* blin   = (const float*)d_in[20];
    const float* Wfin   = (const float*)d_in[21];
    const float* bfin   = (const float*)d_in[22];
    float* outp = (float*)d_out;

    // ---- workspace carve (256B-aligned slabs), ~33 MB ----
    size_t o = 0;
    char* base = (char*)d_ws;
    auto carve = [&](size_t bytes) { void* p = base + o; o += (bytes + 255) & ~(size_t)255; return p; };
    bf16*  h0     = (bf16*)carve((size_t)N_NODES * D * sizeof(bf16));
    bf16*  h1     = (bf16*)carve((size_t)N_NODES * D * sizeof(bf16));
    int*   offs   = (int*)carve((size_t)SCAN_N * sizeof(int));
    int*   srcs   = (int*)carve((size_t)N_EDGES * sizeof(int));
    int*   bcnt   = (int*)carve((size_t)(NBUCK + 1) * sizeof(int));
    int*   bcur   = (int*)carve((size_t)NBUCK * sizeof(int));
    uint*  ebuf   = (uint*)carve((size_t)N_EDGES * sizeof(uint));
    float* hh     = (float*)carve((size_t)N_GRAPHS * D * sizeof(float));
    float* cc     = (float*)carve((size_t)N_GRAPHS * D * sizeof(float));
    float* qstar  = (float*)carve((size_t)N_GRAPHS * 2 * D * sizeof(float));
    int*   gstart = (int*)carve((size_t)(N_GRAPHS + 1) * sizeof(int));
    short* W1p    = (short*)carve((size_t)256 * 128 * sizeof(short));
    short* Wihp   = (short*)carve((size_t)128 * 384 * sizeof(short));
    short* Whhp   = (short*)carve((size_t)128 * 384 * sizeof(short));
    size_t need = o;

    if (ws_size < need) {
        k_signal<<<(out_size + 255) / 256, 256, 0, stream>>>(outp, out_size);
        return;
    }

    // node MLP -> h0
    k_embed<<<N_NODES / NPE, 128, 0, stream>>>(x, Wemb, bemb, Wfirst, bfirst, h0);

    // all weight packing
    k_pack_all<<<(32768 + 98304) / 256, 256, 0, stream>>>(Wl, Wr, gWih, gWhh, W1p, Wihp, Whhp);

    // bucketed CSR build (LDS-aggregated placement)
    hipMemsetAsync(bcnt, 0, (size_t)((char*)ebuf - (char*)bcnt), stream);
    k_bcount<<<128, 256, 0, stream>>>(ei, bcnt);
    k_bscan<<<1, 64, 0, stream>>>(bcnt);
    k_bfill2<<<(N_EDGES + EPB - 1) / EPB, BFT, 0, stream>>>(ei, bcnt, bcur, ebuf);
    k_csr<<<NBUCK, 256, 0, stream>>>(bcnt, ebuf, offs, srcs);

    // graph segment starts
    k_gstart<<<(N_GRAPHS + 1 + 255) / 256, 256, 0, stream>>>(batch, gstart);

    // 3 message-passing steps
    bf16* hc = h0; bf16* hn = h1;
    for (int s = 0; s < 3; s++) {
        k_gather<<<N_NODES / 4, 256, 0, stream>>>(hc, hn, offs, srcs);
        k_sage_gru_mfma<<<(N_NODES + 31) / 32, 128, 0, stream>>>(
            hc, hn, W1p, Wihp, Whhp, bl, gbih, gbhh);
        bf16* tmp = hc; hc = hn; hn = tmp;
    }

    // Set2Set: merged LSTM+pool, 2 graphs/block
    for (int s = 0; s < 3; s++) {
        k_s2s<<<N_GRAPHS / LG2, 1024, 0, stream>>>(lWih, lWhh, lbih, lbhh,
                                                   hc, gstart, qstar, hh, cc, s == 0);
    }

    k_final<<<N_GRAPHS, 128, 0, stream>>>(qstar, Wlin, blin, Wfin, bfin, outp);
}